// Round 3
// baseline (496.071 us; speedup 1.0000x reference)
//
#include <hip/hip_runtime.h>
#include <hip/hip_bf16.h>
#include <cstdint>

// Problem constants
#define NROWS   131072
#define NUNITS  256
#define KTOT    512          // INPUT_DIM + UNITS
#define BM      64
#define THREADS 512

typedef float f32x16 __attribute__((ext_vector_type(16)));
typedef float f32x4  __attribute__((ext_vector_type(4)));
typedef short bf16x8 __attribute__((ext_vector_type(8)));

__device__ __forceinline__ short f2bf(float x) {
    unsigned u = __float_as_uint(x);
    u += 0x7FFFu + ((u >> 16) & 1u);   // round-to-nearest-even
    return (short)(u >> 16);
}

// W [512][1024] fp32 -> Wws[k/16][col][k%16] bf16.
// A wave's 32x32x16 B-fragment (32 cols x 16 k) = contiguous 1 KiB. L2-resident.
__global__ void convert_W_kernel(const float* __restrict__ W, short* __restrict__ Wws) {
    int i = blockIdx.x * 256 + threadIdx.x;       // 0 .. 524287
    int k = i >> 10;
    int c = i & 1023;
    Wws[((size_t)(k >> 4) << 14) + ((size_t)c << 4) + (k & 15)] = f2bf(W[i]);
}

// x,h [131072][256] fp32 -> Aws[row][512] bf16  ([x | h] concatenated per row)
__global__ void convert_A_kernel(const float* __restrict__ x, const float* __restrict__ h,
                                 short* __restrict__ Aws) {
    int i = blockIdx.x * 256 + threadIdx.x;       // 0 .. 8388607
    int row = i >> 6;
    int c   = (i & 63) * 4;
    float4 xv = *(const float4*)(x + (size_t)row * 256 + c);
    float4 hv = *(const float4*)(h + (size_t)row * 256 + c);
    short xs[4] = {f2bf(xv.x), f2bf(xv.y), f2bf(xv.z), f2bf(xv.w)};
    short hs[4] = {f2bf(hv.x), f2bf(hv.y), f2bf(hv.z), f2bf(hv.w)};
    *(uint2*)(Aws + (size_t)row * 512 + c)       = *(uint2*)xs;
    *(uint2*)(Aws + (size_t)row * 512 + 256 + c) = *(uint2*)hs;
}

// Main: barrier-free, LDS-free. Grid 4096 = 2048 row-tiles x 2 col-halves.
// 8 waves = 2 row-groups (32 rows) x 4 col-slices (32 cols/gate).
// mfma_f32_32x32x16_bf16; acc[4 gates] f32x16; all 4 gates lane-local -> fused
// LSTM epilogue in-register. A/B fragments are direct 16B global loads from
// cache-resident fragment-ordered buffers; no __syncthreads -> no vmcnt drains.
template<bool PRE>
__global__ void __launch_bounds__(THREADS, 4)
lstm_main_kernel(const float* __restrict__ x, const float* __restrict__ h_prev,
                 const float* __restrict__ c_prev, const float* __restrict__ bias,
                 const float* __restrict__ pi, const float* __restrict__ pf,
                 const float* __restrict__ po, const short* __restrict__ Wws,
                 const short* __restrict__ Aws, float* __restrict__ out) {
    const int t    = threadIdx.x;
    const int lane = t & 63;
    const int w    = t >> 6;
    const int mg   = w >> 2;            // 0..1  row group
    const int cs   = w & 3;             // 0..3  col slice
    const int rt   = blockIdx.x >> 1;
    const int ch   = blockIdx.x & 1;
    const int l5   = lane & 31;
    const int k8   = lane >> 5;         // k-granule (8 contiguous k)

    const int row  = rt * BM + mg * 32 + l5;    // A row for this lane
    const int u    = ch * 128 + cs * 32 + l5;   // unit col for this lane

    f32x16 acc[4];
    #pragma unroll
    for (int g = 0; g < 4; ++g)
        acc[g] = (f32x16){0.f,0.f,0.f,0.f,0.f,0.f,0.f,0.f,0.f,0.f,0.f,0.f,0.f,0.f,0.f,0.f};

    // B base: col = g*256 + u, k-granule k8; per 16-k step add 16384 shorts
    const short* wbase = Wws + ((size_t)u << 4) + k8 * 8;
    const short* abase = PRE ? (Aws + (size_t)row * 512 + k8 * 8) : nullptr;
    const float* xrow  = x      + (size_t)row * 256;
    const float* hrow  = h_prev + (size_t)row * 256;

    #pragma unroll 2
    for (int it = 0; it < 16; ++it) {
        const int k0 = it * 32;
        bf16x8 A0, A1;
        if (PRE) {
            A0 = *(const bf16x8*)(abase + k0);
            A1 = *(const bf16x8*)(abase + k0 + 16);
        } else {
            const int ka = k0 + k8 * 8;
            const int kb = ka + 16;
            const float* sa = (ka < 256) ? (xrow + ka) : (hrow + ka - 256);
            const float* sb = (kb < 256) ? (xrow + kb) : (hrow + kb - 256);
            float4 va0 = *(const float4*)sa, va1 = *(const float4*)(sa + 4);
            float4 vb0 = *(const float4*)sb, vb1 = *(const float4*)(sb + 4);
            short a0[8] = {f2bf(va0.x), f2bf(va0.y), f2bf(va0.z), f2bf(va0.w),
                           f2bf(va1.x), f2bf(va1.y), f2bf(va1.z), f2bf(va1.w)};
            short a1[8] = {f2bf(vb0.x), f2bf(vb0.y), f2bf(vb0.z), f2bf(vb0.w),
                           f2bf(vb1.x), f2bf(vb1.y), f2bf(vb1.z), f2bf(vb1.w)};
            A0 = *(bf16x8*)a0;
            A1 = *(bf16x8*)a1;
        }
        const short* wk0 = wbase + ((size_t)(2 * it) << 14);
        const short* wk1 = wk0 + 16384;
        #pragma unroll
        for (int g = 0; g < 4; ++g) {
            bf16x8 B0 = *(const bf16x8*)(wk0 + g * 4096);
            bf16x8 B1 = *(const bf16x8*)(wk1 + g * 4096);
            acc[g] = __builtin_amdgcn_mfma_f32_32x32x16_bf16(A0, B0, acc[g], 0, 0, 0);
            acc[g] = __builtin_amdgcn_mfma_f32_32x32x16_bf16(A1, B1, acc[g], 0, 0, 0);
        }
    }

    // ---- fused LSTM epilogue (lane-local) ----
    // C/D layout: col = lane&31, row = (reg&3) + 8*(reg>>2) + 4*(lane>>5)
    const size_t HS = (size_t)NROWS * NUNITS;
    const float bi = bias[u],       bfg = bias[256 + u];
    const float bc = bias[512 + u], bo  = bias[768 + u];
    const float ppi = pi[u], ppf = pf[u], ppo = po[u];
    const int rowbase = rt * BM + mg * 32 + 4 * k8;
    #pragma unroll
    for (int r = 0; r < 16; ++r) {
        const int rr = rowbase + (r & 3) + 8 * (r >> 2);
        const size_t o = (size_t)rr * NUNITS + u;
        const float cp = c_prev[o];
        float zi = acc[0][r] + bi  + ppi * cp;
        float zf = acc[1][r] + bfg + ppf * cp;
        float zc = acc[2][r] + bc;
        float zo = acc[3][r] + bo  + ppo * cp;
        float ig = 1.f / (1.f + __expf(-zi));
        float fg = 1.f / (1.f + __expf(-zf));
        float og = 1.f / (1.f + __expf(-zo));
        zc = fminf(fmaxf(zc, -30.f), 30.f);
        float e2 = __expf(2.f * zc);
        float chat = (e2 - 1.f) / (e2 + 1.f);
        float c  = fg * cp + ig * chat;
        float ccl = fminf(fmaxf(c, -30.f), 30.f);
        float e3 = __expf(2.f * ccl);
        float th = (e3 - 1.f) / (e3 + 1.f);
        float h  = og * th;
        out[o]          = h;
        out[HS + o]     = h;
        out[2 * HS + o] = c;
    }
}

extern "C" void kernel_launch(void* const* d_in, const int* in_sizes, int n_in,
                              void* d_out, int out_size, void* d_ws, size_t ws_size,
                              hipStream_t stream) {
    const float* x  = (const float*)d_in[0];
    const float* h  = (const float*)d_in[1];
    const float* c  = (const float*)d_in[2];
    const float* W  = (const float*)d_in[3];
    const float* b  = (const float*)d_in[4];
    const float* pi = (const float*)d_in[5];
    const float* pf = (const float*)d_in[6];
    const float* po = (const float*)d_in[7];
    float* out = (float*)d_out;

    const size_t aws_bytes = (size_t)NROWS * KTOT * 2;        // 134,217,728
    const size_t wws_bytes = (size_t)KTOT * 1024 * 2;         // 1,048,576

    if (ws_size >= aws_bytes + wws_bytes) {
        short* Aws = (short*)d_ws;
        short* Wws = (short*)((char*)d_ws + aws_bytes);
        hipLaunchKernelGGL(convert_A_kernel, dim3(32768), dim3(256), 0, stream, x, h, Aws);
        hipLaunchKernelGGL(convert_W_kernel, dim3(2048), dim3(256), 0, stream, W, Wws);
        hipLaunchKernelGGL((lstm_main_kernel<true>), dim3(2 * NROWS / BM), dim3(THREADS), 0,
                           stream, x, h, c, b, pi, pf, po, Wws, Aws, out);
    } else {
        short* Wws = (short*)d_ws;
        hipLaunchKernelGGL(convert_W_kernel, dim3(2048), dim3(256), 0, stream, W, Wws);
        hipLaunchKernelGGL((lstm_main_kernel<false>), dim3(2 * NROWS / BM), dim3(THREADS), 0,
                           stream, x, h, c, b, pi, pf, po, Wws, nullptr, out);
    }
}

// Round 4
// 347.551 us; speedup vs baseline: 1.4273x; 1.4273x over previous
//
#include <hip/hip_runtime.h>
#include <hip/hip_bf16.h>
#include <cstdint>

// Problem constants
#define NROWS   131072
#define NUNITS  256
#define KTOT    512          // INPUT_DIM + UNITS
#define BM      64
#define THREADS 512

typedef float f32x4  __attribute__((ext_vector_type(4)));
typedef short bf16x8 __attribute__((ext_vector_type(8)));

__device__ __forceinline__ short f2bf(float x) {
    unsigned u = __float_as_uint(x);
    u += 0x7FFFu + ((u >> 16) & 1u);   // round-to-nearest-even
    return (short)(u >> 16);
}

// Raw barrier: drain only LDS ops (cross-wave A-tile visibility); global
// prefetch loads stay in flight across the barrier (counted-vmcnt pipeline).
#define BAR() do { asm volatile("s_waitcnt lgkmcnt(0)" ::: "memory"); \
                   __builtin_amdgcn_s_barrier(); } while (0)

// W [512][1024] fp32  ->  Wws [16][1024][32] bf16 (B-fragment order, L2-resident)
__global__ void convert_W_kernel(const float* __restrict__ W, short* __restrict__ Wws) {
    int i = blockIdx.x * 256 + threadIdx.x;       // 0 .. 524287
    int k = i >> 10;
    int c = i & 1023;
    Wws[((size_t)(k >> 5) << 15) + ((size_t)c << 5) + (k & 31)] = f2bf(W[i]);
}

// Grid 4096 = 2048 row-tiles x 2 col-halves, XCD-swizzled.
// Block: 8 waves; wave w owns cols {g*256 + ch*128 + w*16 + lr} for all 4 gates.
// A double-buffered in LDS (XOR-swizzled, conflict-free); B prefetched one
// k-step ahead into registers; raw s_barrier without vmcnt drain.
__global__ void __launch_bounds__(THREADS, 4)
lstm_main_kernel(const float* __restrict__ x, const float* __restrict__ h_prev,
                 const float* __restrict__ c_prev, const float* __restrict__ bias,
                 const float* __restrict__ pi, const float* __restrict__ pf,
                 const float* __restrict__ po, const short* __restrict__ Wws,
                 float* __restrict__ out) {
    __shared__ short Alds[2][BM * 32];   // 2 x 4 KiB

    // XCD-aware bijective swizzle: 4096 blocks = 8 XCDs x 512-chunk.
    // ch-pair (rt,0)/(rt,1) maps to bids b,b+8 -> same XCD, adjacent dispatch.
    const int bid = blockIdx.x;
    const int swz = (bid & 7) * 512 + (bid >> 3);
    const int rt  = swz >> 1;
    const int ch  = swz & 1;
    const int row0 = rt * BM;

    const int t    = threadIdx.x;
    const int lane = t & 63;
    const int w    = t >> 6;
    const int lr   = lane & 15;
    const int hi   = lane >> 4;          // k-granule 0..3

    // ---- staging indices: thread -> one float4 of the 64x32 A tile ----
    const int srow  = t >> 3;            // 0..63
    const int sh    = t & 7;             // float4 index within 32-k row
    const int sg    = sh >> 1;
    const int shalf = sh & 1;
    const int s_lds = srow * 32 + ((sg ^ ((srow >> 1) & 3)) * 8) + shalf * 4;
    const float* aRowX = x      + (size_t)(row0 + srow) * 256 + sh * 4;
    const float* aRowH = h_prev + (size_t)(row0 + srow) * 256 + sh * 4;

    // ---- fragment read offset (shorts): row=m*16+lr, swizzled granule ----
    const int a_rd = lr * 32 + ((hi ^ ((lr >> 1) & 3)) * 8);   // + m*16*32

    // ---- B-fragment base: col = g*256 + ch*128 + w*16 + lr ----
    const int ucol = ch * 128 + w * 16 + lr;
    const short* wbase = Wws + ((size_t)ucol << 5) + hi * 8;   // + ks*32768 + g*8192

    f32x4 acc[4][4];
    #pragma unroll
    for (int m = 0; m < 4; ++m)
        #pragma unroll
        for (int g = 0; g < 4; ++g)
            acc[m][g] = (f32x4){0.f, 0.f, 0.f, 0.f};

    bf16x8 Bcur[4], Bnext[4];

    auto loadA4 = [&](int kidx) -> float4 {
        return *(const float4*)((kidx < 8 ? aRowX : aRowH) + (kidx & 7) * 32);
    };
    auto writeA = [&](float4 av, int buf) {
        unsigned p0 = ((unsigned)(unsigned short)f2bf(av.y) << 16) | (unsigned short)f2bf(av.x);
        unsigned p1 = ((unsigned)(unsigned short)f2bf(av.w) << 16) | (unsigned short)f2bf(av.z);
        *(uint2*)(&Alds[buf][s_lds]) = make_uint2(p0, p1);
    };
    auto loadB = [&](int ks, bf16x8* B) {
        const short* wk = wbase + ((size_t)ks << 15);
        #pragma unroll
        for (int g = 0; g < 4; ++g)
            B[g] = *(const bf16x8*)(wk + g * 8192);
    };
    auto compute = [&](const bf16x8* B, int buf) {
        bf16x8 af[4];
        #pragma unroll
        for (int m = 0; m < 4; ++m)
            af[m] = *(const bf16x8*)&Alds[buf][a_rd + m * 16 * 32];
        #pragma unroll
        for (int g = 0; g < 4; ++g)
            #pragma unroll
            for (int m = 0; m < 4; ++m)
                acc[m][g] = __builtin_amdgcn_mfma_f32_16x16x32_bf16(af[m], B[g], acc[m][g], 0, 0, 0);
    };

    // ---- prologue: stage k=0, load B(0) ----
    {
        float4 av0 = loadA4(0);
        loadB(0, Bcur);
        writeA(av0, 0);
        BAR();
    }

    // ---- steady state: 7 x 2 k-steps, prefetch one step ahead ----
    #pragma unroll 1
    for (int it2 = 0; it2 < 7; ++it2) {
        const int k0 = 2 * it2;
        {   // compute k0 (buf0, Bcur); prep k0+1 -> buf1, Bnext
            float4 av = loadA4(k0 + 1);
            loadB(k0 + 1, Bnext);
            compute(Bcur, 0);
            writeA(av, 1);
            BAR();
        }
        {   // compute k0+1 (buf1, Bnext); prep k0+2 -> buf0, Bcur
            float4 av = loadA4(k0 + 2);
            loadB(k0 + 2, Bcur);
            compute(Bnext, 1);
            writeA(av, 0);
            BAR();
        }
    }
    // ---- tail: k=14 (prep 15), k=15 ----
    {
        float4 av = loadA4(15);
        loadB(15, Bnext);
        compute(Bcur, 0);
        writeA(av, 1);
        BAR();
        compute(Bnext, 1);
    }

    // ---- fused LSTM epilogue (lane-local: all 4 gates in acc[m][0..3]) ----
    const size_t HS = (size_t)NROWS * NUNITS;
    const int u = ucol;
    const float bi = bias[u],       bfg = bias[256 + u];
    const float bc = bias[512 + u], bo  = bias[768 + u];
    const float ppi = pi[u], ppf = pf[u], ppo = po[u];
    #pragma unroll
    for (int m = 0; m < 4; ++m) {
        #pragma unroll
        for (int r = 0; r < 4; ++r) {
            const int row = row0 + m * 16 + hi * 4 + r;
            const size_t o = (size_t)row * NUNITS + u;
            const float cp = c_prev[o];
            float zi = acc[m][0][r] + bi  + ppi * cp;
            float zf = acc[m][1][r] + bfg + ppf * cp;
            float zc = acc[m][2][r] + bc;
            float zo = acc[m][3][r] + bo  + ppo * cp;
            float ig = 1.f / (1.f + __expf(-zi));
            float fg = 1.f / (1.f + __expf(-zf));
            float og = 1.f / (1.f + __expf(-zo));
            zc = fminf(fmaxf(zc, -30.f), 30.f);
            float e2 = __expf(2.f * zc);
            float chat = (e2 - 1.f) / (e2 + 1.f);
            float c  = fg * cp + ig * chat;
            float ccl = fminf(fmaxf(c, -30.f), 30.f);
            float e3 = __expf(2.f * ccl);
            float th = (e3 - 1.f) / (e3 + 1.f);
            float h  = og * th;
            out[o]          = h;
            out[HS + o]     = h;
            out[2 * HS + o] = c;
        }
    }
}

extern "C" void kernel_launch(void* const* d_in, const int* in_sizes, int n_in,
                              void* d_out, int out_size, void* d_ws, size_t ws_size,
                              hipStream_t stream) {
    const float* x  = (const float*)d_in[0];
    const float* h  = (const float*)d_in[1];
    const float* c  = (const float*)d_in[2];
    const float* W  = (const float*)d_in[3];
    const float* b  = (const float*)d_in[4];
    const float* pi = (const float*)d_in[5];
    const float* pf = (const float*)d_in[6];
    const float* po = (const float*)d_in[7];
    short* Wws = (short*)d_ws;            // 1 MiB bf16 copy of W in B-frag order
    float* out = (float*)d_out;

    hipLaunchKernelGGL(convert_W_kernel, dim3(2048), dim3(256), 0, stream, W, Wws);
    hipLaunchKernelGGL(lstm_main_kernel, dim3(2 * NROWS / BM), dim3(THREADS), 0, stream,
                       x, h, c, b, pi, pf, po, Wws, out);
}